// Round 7
// baseline (135.802 us; speedup 1.0000x reference)
//
#include <hip/hip_runtime.h>
#include <hip/hip_fp16.h>
#include <math.h>

#define NQ 10
#define NL 4
#define NA (NQ * NL)
#define PI_F 3.14159265358979323846f
#define INV_2PI_F 0.15915494309189535f

typedef _Float16 h2 __attribute__((ext_vector_type(2)));

// ---------- packed-f16 complex helpers; amp layout: bits[15:0]=re, [31:16]=im ----------
// cmul_sg<SR,SI>(c,s) = (SR*c.re, SI*c.im) complex-multiplied with s. (HW-validated R4/R7)
template <int SR, int SI>
__device__ __forceinline__ unsigned cmul_sg(unsigned c, unsigned s) {
  unsigned d;
  if constexpr (SR > 0) {
    asm("v_pk_mul_f16 %0, %1, %2 op_sel_hi:[0,1]" : "=v"(d) : "v"(c), "v"(s));
  } else {
    asm("v_pk_mul_f16 %0, %1, %2 op_sel_hi:[0,1] neg_lo:[1,0] neg_hi:[1,0]"
        : "=v"(d) : "v"(c), "v"(s));
  }
  if constexpr (SI > 0) {
    asm("v_pk_fma_f16 %0, %1, %2, %0 op_sel:[1,1,0] op_sel_hi:[1,0,1] neg_lo:[1,0,0]"
        : "+v"(d) : "v"(c), "v"(s));
  } else {
    asm("v_pk_fma_f16 %0, %1, %2, %0 op_sel:[1,1,0] op_sel_hi:[1,0,1] neg_hi:[1,0,0]"
        : "+v"(d) : "v"(c), "v"(s));
  }
  return d;
}

template <int SR, int SI>
__device__ __forceinline__ unsigned cfma_sg(unsigned c, unsigned s, unsigned acc) {
  unsigned d;
  if constexpr (SR > 0) {
    asm("v_pk_fma_f16 %0, %1, %2, %3 op_sel_hi:[0,1,1]"
        : "=v"(d) : "v"(c), "v"(s), "v"(acc));
  } else {
    asm("v_pk_fma_f16 %0, %1, %2, %3 op_sel_hi:[0,1,1] neg_lo:[1,0,0] neg_hi:[1,0,0]"
        : "=v"(d) : "v"(c), "v"(s), "v"(acc));
  }
  if constexpr (SI > 0) {
    asm("v_pk_fma_f16 %0, %1, %2, %0 op_sel:[1,1,0] op_sel_hi:[1,0,1] neg_lo:[1,0,0]"
        : "+v"(d) : "v"(c), "v"(s));
  } else {
    asm("v_pk_fma_f16 %0, %1, %2, %0 op_sel:[1,1,0] op_sel_hi:[1,0,1] neg_hi:[1,0,0]"
        : "+v"(d) : "v"(c), "v"(s));
  }
  return d;
}

// ---------- lane-crossing ----------
// R7 two-pipe model (from R4/R5 A/B): dur = max(VALU_time, DS_time); pipes
// were near-balanced, so cut DS hard while adding only cheap DPP movs:
//   mask 1: quad_perm xor1 (VALU)      mask 2: quad_perm xor2 (VALU)
//   mask 4: row_half_mirror (xor7) + quad_perm[3,2,1,0] (xor3) = xor4, 2 VALU
//           (pure movs, no copy overhead — unlike R5's permlane-swap trap)
//   mask 8: row_ror:8 (VALU)           mask 16: ds_swizzle (DS)
//   mask 32: ds_permute via __shfl_xor (DS)
template <int MASK>
__device__ __forceinline__ int ishfl_xor(int v) {
  if constexpr (MASK == 1) {
    return __builtin_amdgcn_update_dpp(v, v, 0xB1, 0xF, 0xF, true);
  } else if constexpr (MASK == 2) {
    return __builtin_amdgcn_update_dpp(v, v, 0x4E, 0xF, 0xF, true);
  } else if constexpr (MASK == 4) {
    int t = __builtin_amdgcn_update_dpp(v, v, 0x141, 0xF, 0xF, true);  // xor7
    return __builtin_amdgcn_update_dpp(t, t, 0x1B, 0xF, 0xF, true);    // xor3
  } else if constexpr (MASK == 8) {
    return __builtin_amdgcn_update_dpp(v, v, 0x128, 0xF, 0xF, true);
  } else if constexpr (MASK == 16) {
    return __builtin_amdgcn_ds_swizzle(v, 0x401F);
  } else {
    return __shfl_xor(v, MASK, 64);
  }
}

template <int MASK>
__device__ __forceinline__ float fshfl_xor(float v) {
  return __int_as_float(ishfl_xor<MASK>(__float_as_int(v)));
}

__device__ __forceinline__ unsigned readlane_u(unsigned v, int l) {
  return (unsigned)__builtin_amdgcn_readlane((int)v, l);
}

__device__ __forceinline__ float wave_sum_h(float v) {
  v += fshfl_xor<1>(v);
  v += fshfl_xor<2>(v);
  v += fshfl_xor<4>(v);
  v += fshfl_xor<8>(v);
  v += fshfl_xor<16>(v);
  v += fshfl_xor<32>(v);
  return v;
}

// Round-to-nearest f16 pack (cvt_pkrtz is RTZ -> R6's 1.5% norm contraction).
__device__ __forceinline__ unsigned pack_h2_rtn(float re, float im) {
  return (unsigned)__half_as_ushort(__float2half(re)) |
         ((unsigned)__half_as_ushort(__float2half(im)) << 16);
}

// Cross gate on lane bit LB, both elements, full 16 regs.
// DEF=true (only used with LB=5): the preceding ring's q9 xor32 on ODD regs
// was deferred (not physically applied). For odd r the stored value st
// satisfies true = xor32(st), so the gate's own xor32 cancels:
//   p = xor32(st) = true@own-lane, s = st = true@partner-lane
//   new = A*p + B*s   (operand roles swapped vs normal new = A*s + B*p)
// After this gate the stored layout is back to true layout. Zero extra cost.
template <int LB, bool DEF = false>
__device__ __forceinline__ void cross_gate2(unsigned (&sv)[2][16],
                                            const unsigned (&u00)[2],
                                            const unsigned (&u01)[2], int lane) {
  const bool bit = (lane & (1 << LB)) != 0;
  unsigned A[2], B[2];
#pragma unroll
  for (int e = 0; e < 2; ++e) {
    A[e] = bit ? (u00[e] ^ 0x80000000u) : u00[e];
    B[e] = bit ? (u01[e] ^ 0x00008000u) : u01[e];
  }
#pragma unroll
  for (int r = 0; r < 16; ++r) {
    unsigned p0 = (unsigned)ishfl_xor<(1 << LB)>((int)sv[0][r]);
    unsigned p1 = (unsigned)ishfl_xor<(1 << LB)>((int)sv[1][r]);
    if (DEF && (r & 1)) {
      // deferred odd reg: new = A*p + B*s
      sv[0][r] = cfma_sg<1, 1>(B[0], sv[0][r], cmul_sg<1, 1>(A[0], p0));
      sv[1][r] = cfma_sg<1, 1>(B[1], sv[1][r], cmul_sg<1, 1>(A[1], p1));
    } else {
      sv[0][r] = cfma_sg<1, 1>(B[0], p0, cmul_sg<1, 1>(A[0], sv[0][r]));
      sv[1][r] = cfma_sg<1, 1>(B[1], p1, cmul_sg<1, 1>(A[1], sv[1][r]));
    }
  }
}

// Layer-0 cross gate: regs 1..15 are exactly zero, only r=0 carries amplitude.
template <int LB>
__device__ __forceinline__ void cross_gate2_r0(unsigned (&sv)[2][16],
                                               const unsigned (&u00)[2],
                                               const unsigned (&u01)[2], int lane) {
  const bool bit = (lane & (1 << LB)) != 0;
#pragma unroll
  for (int e = 0; e < 2; ++e) {
    const unsigned A = bit ? (u00[e] ^ 0x80000000u) : u00[e];
    const unsigned B = bit ? (u01[e] ^ 0x00008000u) : u01[e];
    unsigned p = (unsigned)ishfl_xor<(1 << LB)>((int)sv[e][0]);
    sv[e][0] = cfma_sg<1, 1>(B, p, cmul_sg<1, 1>(A, sv[e][0]));
  }
}

// Register-local gate on reg bit RB, full (both pair halves nonzero).
template <int RB>
__device__ __forceinline__ void local_gate2(unsigned (&sv)[2][16],
                                            const unsigned (&u00)[2],
                                            const unsigned (&u01)[2]) {
#pragma unroll
  for (int rlo = 0; rlo < 16; ++rlo) {
    if (rlo & (1 << RB)) continue;
    const int rhi = rlo | (1 << RB);
#pragma unroll
    for (int e = 0; e < 2; ++e) {
      unsigned lo = sv[e][rlo], hi = sv[e][rhi];
      sv[e][rlo] = cfma_sg<1, 1>(u01[e], hi, cmul_sg<1, 1>(u00[e], lo));
      sv[e][rhi] = cfma_sg<1, -1>(u00[e], hi, cmul_sg<-1, 1>(u01[e], lo));
    }
  }
}

// Layer-0 local gate: live regs before gate RB are {r : r & ((2<<RB)-1) == 0};
// hi half of every pair is exactly zero -> pure cmul fill (2 pk each).
// lo' = u00*lo ; hi' = -conj(u01)*lo.
template <int RB>
__device__ __forceinline__ void local_gate2_fill(unsigned (&sv)[2][16],
                                                 const unsigned (&u00)[2],
                                                 const unsigned (&u01)[2]) {
#pragma unroll
  for (int rlo = 0; rlo < 16; ++rlo) {
    if (rlo & ((2 << RB) - 1)) continue;  // only live, pair-base regs
    const int rhi = rlo | (1 << RB);
#pragma unroll
    for (int e = 0; e < 2; ++e) {
      unsigned lo = sv[e][rlo];
      sv[e][rhi] = cmul_sg<-1, 1>(u01[e], lo);
      sv[e][rlo] = cmul_sg<1, 1>(u00[e], lo);
    }
  }
}

// CNOT ring, q -> q+1 mod 10 (composed), both elements.
// apply_q9=false: leave q9's xor32 on odd regs PENDING (consumed by the next
// layer's wire0 gate via cross_gate2<5,true>). Saves 16 DS ops per ring.
__device__ __forceinline__ void ring_step(unsigned (&sv)[2][16], int lane,
                                          int permSrc, bool apply_q9) {
  // q=0..4 composed: lane gather from gray(lane)
#pragma unroll
  for (int r = 0; r < 16; ++r) {
    sv[0][r] = (unsigned)__shfl((int)sv[0][r], permSrc);
    sv[1][r] = (unsigned)__shfl((int)sv[1][r], permSrc);
  }
  // q=5: control wire5 = lane bit0, target wire6 = reg bit3 -> cond swap r<->r^8
  {
    const bool c5 = (lane & 1) != 0;
#pragma unroll
    for (int r = 0; r < 8; ++r) {
#pragma unroll
      for (int e = 0; e < 2; ++e) {
        unsigned a = sv[e][r], b = sv[e][r + 8];
        sv[e][r] = c5 ? b : a;
        sv[e][r + 8] = c5 ? a : b;
      }
    }
  }
  // q=6..8 composed: register gather new[j] = old[gray(j)]
#pragma unroll
  for (int e = 0; e < 2; ++e) {
    unsigned t;
    t = sv[e][2]; sv[e][2] = sv[e][3]; sv[e][3] = t;
    t = sv[e][4]; sv[e][4] = sv[e][6]; sv[e][6] = sv[e][5]; sv[e][5] = sv[e][7]; sv[e][7] = t;
    t = sv[e][8]; sv[e][8] = sv[e][12]; sv[e][12] = sv[e][10]; sv[e][10] = sv[e][15]; sv[e][15] = t;
    t = sv[e][9]; sv[e][9] = sv[e][13]; sv[e][13] = sv[e][11]; sv[e][11] = sv[e][14]; sv[e][14] = t;
  }
  // q=9: control wire9 = reg bit0, target wire0 = lane bit5 -> odd r: xor32
  if (apply_q9) {
#pragma unroll
    for (int r = 1; r < 16; r += 2) {
      sv[0][r] = (unsigned)ishfl_xor<32>((int)sv[0][r]);
      sv[1][r] = (unsigned)ishfl_xor<32>((int)sv[1][r]);
    }
  }
}

// One wave simulates 2 batch elements (register-interleaved). State index
// i = lane*16 + r. Wire q at bit (9-q): wires 0..5 -> lane bits 5..0,
// wires 6..9 -> reg bits 3..0.
// Layer 0 runs a sparsity-specialized path (|0...0> start) — bit-identical.
// R11 lesson (NE=4): TLP, not ILP — NE=2 is the sweet spot.
// R12/R13 lessons -> two-pipe model: dur = max(VALU_time, DS_time), pipes
// were balanced (~72us each). R7 (this round): cut DS ~48% (e-split revert,
// xor4 via 2 DPP, ring-q9 deferral into next wire0 gate) at +3% VALU.
// No launch_bounds (R14: attribute was not the occupancy cap; this compiles
// identically at 40 VGPR, no scratch).
__global__ void qsim_kernel(
    const float* __restrict__ x, const float* __restrict__ w,
    float* __restrict__ out, int batch) {
  const int lane = threadIdx.x & 63;
  const int wv = blockIdx.x * 4 + (threadIdx.x >> 6);
  const int permSrc = lane ^ (lane >> 1);  // composed CNOT(q,q+1), q=0..4

  // weight-only gate factors: lane j<40 owns gate j = l*10+q
  float Pr = 0.f, Pi = 0.f, Qr = 0.f, Qi = 0.f;
  if (lane < NA) {
    float w0 = w[2 * lane], w1 = w[2 * lane + 1];
    // sin/cos of 0.5*w0, 0.5*w1 via HW trig (input in revolutions)
    float r0 = w0 * (0.5f * INV_2PI_F), r1 = w1 * (0.5f * INV_2PI_F);
    float sphi = __builtin_amdgcn_sinf(r0), cphi = __builtin_amdgcn_cosf(r0);
    float sw = __builtin_amdgcn_sinf(r1), cw = __builtin_amdgcn_cosf(r1);
    Pr = cw * cphi; Pi = -cw * sphi;  // P = cos(w1/2) e^{-i w0/2}
    Qr = sw * cphi; Qi = sw * sphi;   // Q = sin(w1/2) e^{+i w0/2}
  }

  // ---- prologue for both elements: SU(2) coefs packed f16 (RTN) ----
  unsigned U00[2] = {0u, 0u}, U01[2] = {0u, 0u};
#pragma unroll
  for (int e = 0; e < 2; ++e) {
    const int wid = wv * 2 + e;
    const int widc = wid < batch ? wid : batch - 1;
    if (lane < NA) {
      float xv = x[widc * NA + lane];
      // a = (pi/2)*atan(x) radians -> atan(x)/4 revolutions
      float rev = 0.25f * atanf(xv);
      float sa = __builtin_amdgcn_sinf(rev);
      float ca = __builtin_amdgcn_cosf(rev);
      float u00r = ca * Pr - sa * Qr;
      float u00i = ca * Pi - sa * Qi;
      float u01r = -(sa * Pr + ca * Qr);
      float u01i = -(sa * Pi + ca * Qi);
      U00[e] = pack_h2_rtn(u00r, u00i);
      U01[e] = pack_h2_rtn(u01r, u01i);
    }
  }

  unsigned sv[2][16];
#pragma unroll
  for (int r = 0; r < 16; ++r) { sv[0][r] = 0u; sv[1][r] = 0u; }
  if (lane == 0) { sv[0][0] = 0x3C00u; sv[1][0] = 0x3C00u; }  // |0...0>

#define GET_U(j)                                                     \
  const unsigned u00[2] = {readlane_u(U00[0], (j)), readlane_u(U00[1], (j))}; \
  const unsigned u01[2] = {readlane_u(U01[0], (j)), readlane_u(U01[1], (j))}

  // ---------- layer 0: sparsity-specialized ----------
  { GET_U(0); cross_gate2_r0<5>(sv, u00, u01, lane); }  // wire0
  { GET_U(1); cross_gate2_r0<4>(sv, u00, u01, lane); }  // wire1
  { GET_U(2); cross_gate2_r0<3>(sv, u00, u01, lane); }  // wire2
  { GET_U(3); cross_gate2_r0<2>(sv, u00, u01, lane); }  // wire3
  { GET_U(4); cross_gate2_r0<1>(sv, u00, u01, lane); }  // wire4
  { GET_U(5); cross_gate2_r0<0>(sv, u00, u01, lane); }  // wire5
  { GET_U(6); local_gate2_fill<3>(sv, u00, u01); }      // wire6: 1 -> 2 live
  { GET_U(7); local_gate2_fill<2>(sv, u00, u01); }      // wire7: 2 -> 4
  { GET_U(8); local_gate2_fill<1>(sv, u00, u01); }      // wire8: 4 -> 8
  { GET_U(9); local_gate2_fill<0>(sv, u00, u01); }      // wire9: 8 -> 16
  ring_step(sv, lane, permSrc, /*apply_q9=*/false);     // q9 deferred -> layer1 wire0

  // ---------- layers 1..3: dense ----------
#pragma unroll 1
  for (int l = 1; l < NL; ++l) {
    const int j0 = l * NQ;
    // wire0 consumes the deferred q9 xor32 (odd regs) from the previous ring
    { GET_U(j0 + 0); cross_gate2<5, true>(sv, u00, u01, lane); }
    { GET_U(j0 + 1); cross_gate2<4>(sv, u00, u01, lane); }  // wire1: lane bit4
    { GET_U(j0 + 2); cross_gate2<3>(sv, u00, u01, lane); }  // wire2: lane bit3
    { GET_U(j0 + 3); cross_gate2<2>(sv, u00, u01, lane); }  // wire3: lane bit2
    { GET_U(j0 + 4); cross_gate2<1>(sv, u00, u01, lane); }  // wire4: lane bit1
    { GET_U(j0 + 5); cross_gate2<0>(sv, u00, u01, lane); }  // wire5: lane bit0
    { GET_U(j0 + 6); local_gate2<3>(sv, u00, u01); }        // wire6: reg bit3
    { GET_U(j0 + 7); local_gate2<2>(sv, u00, u01); }        // wire7: reg bit2
    { GET_U(j0 + 8); local_gate2<1>(sv, u00, u01); }        // wire8: reg bit1
    { GET_U(j0 + 9); local_gate2<0>(sv, u00, u01); }        // wire9: reg bit0
    // rings after layers 1,2: defer q9; ring after layer 3: apply (epilogue
    // needs true layout)
    ring_step(sv, lane, permSrc, /*apply_q9=*/(l == NL - 1));
  }
#undef GET_U

  // ---------- epilogue (f32, v_dot2_f32_f16 accumulation), per element ----------
#pragma unroll
  for (int e = 0; e < 2; ++e) {
    const int wid = wv * 2 + e;
    float tot = 0.f, t0 = 0.f, t1 = 0.f, t2 = 0.f, t3 = 0.f;
#pragma unroll
    for (int r = 0; r < 16; ++r) {
      h2 a = __builtin_bit_cast(h2, sv[e][r]);
      tot = __builtin_amdgcn_fdot2(a, a, tot, false);
      if (r & 1) t0 = __builtin_amdgcn_fdot2(a, a, t0, false);
      if (r & 2) t1 = __builtin_amdgcn_fdot2(a, a, t1, false);
      if (r & 4) t2 = __builtin_amdgcn_fdot2(a, a, t2, false);
      if (r & 8) t3 = __builtin_amdgcn_fdot2(a, a, t3, false);
    }
    const float S3 = wave_sum_h(t3);
    const float S2 = wave_sum_h(t2);
    const float S1 = wave_sum_h(t1);
    const float S0 = wave_sum_h(t0);
    // renormalize: true Z = (P0-P1)/(P0+P1) cancels f16 norm drift
    const float N = wave_sum_h(tot);
    const float invN = 1.0f / N;
    // Walsh-Hadamard across lanes: lane L holds sum_i (-1)^popcnt(L&i) tot_i.
    float v = tot, h;
    h = fshfl_xor<1>(v);  v = (lane & 1)  ? h - v : v + h;
    h = fshfl_xor<2>(v);  v = (lane & 2)  ? h - v : v + h;
    h = fshfl_xor<4>(v);  v = (lane & 4)  ? h - v : v + h;
    h = fshfl_xor<8>(v);  v = (lane & 8)  ? h - v : v + h;
    h = fshfl_xor<16>(v); v = (lane & 16) ? h - v : v + h;
    h = fshfl_xor<32>(v); v = (lane & 32) ? h - v : v + h;

    if (wid < batch) {
      float* o = out + wid * NQ;
      if (lane == 32) o[0] = v * invN;  // wire0 sign = lane bit5
      if (lane == 16) o[1] = v * invN;
      if (lane == 8)  o[2] = v * invN;
      if (lane == 4)  o[3] = v * invN;
      if (lane == 2)  o[4] = v * invN;
      if (lane == 1)  o[5] = v * invN;  // wire5 sign = lane bit0
      if (lane == 0) {
        o[6] = (v - 2.f * S3) * invN;  // wire6 = reg bit3; v(lane0) = sum(tot)
        o[7] = (v - 2.f * S2) * invN;
        o[8] = (v - 2.f * S1) * invN;
        o[9] = (v - 2.f * S0) * invN;
      }
    }
  }
}

extern "C" void kernel_launch(void* const* d_in, const int* in_sizes, int n_in,
                              void* d_out, int out_size, void* d_ws, size_t ws_size,
                              hipStream_t stream) {
  const float* x = (const float*)d_in[0];
  const float* w = (const float*)d_in[1];
  float* out = (float*)d_out;
  const int batch = in_sizes[0] / NA;
  const int waves = (batch + 1) / 2;   // 2 elements per wave
  const int blocks = (waves + 3) / 4;  // 4 independent waves per 256-thread block
  qsim_kernel<<<blocks, 256, 0, stream>>>(x, w, out, batch);
}

// Round 8
// 131.059 us; speedup vs baseline: 1.0362x; 1.0362x over previous
//
#include <hip/hip_runtime.h>
#include <hip/hip_fp16.h>
#include <math.h>

#define NQ 10
#define NL 4
#define NA (NQ * NL)
#define PI_F 3.14159265358979323846f
#define INV_2PI_F 0.15915494309189535f

typedef _Float16 h2 __attribute__((ext_vector_type(2)));

// ---------- packed-f16 complex helpers; amp layout: bits[15:0]=re, [31:16]=im ----------
// cmul_sg<SR,SI>(c,s) = (SR*c.re, SI*c.im) complex-multiplied with s. (HW-validated R4/R7)
template <int SR, int SI>
__device__ __forceinline__ unsigned cmul_sg(unsigned c, unsigned s) {
  unsigned d;
  if constexpr (SR > 0) {
    asm("v_pk_mul_f16 %0, %1, %2 op_sel_hi:[0,1]" : "=v"(d) : "v"(c), "v"(s));
  } else {
    asm("v_pk_mul_f16 %0, %1, %2 op_sel_hi:[0,1] neg_lo:[1,0] neg_hi:[1,0]"
        : "=v"(d) : "v"(c), "v"(s));
  }
  if constexpr (SI > 0) {
    asm("v_pk_fma_f16 %0, %1, %2, %0 op_sel:[1,1,0] op_sel_hi:[1,0,1] neg_lo:[1,0,0]"
        : "+v"(d) : "v"(c), "v"(s));
  } else {
    asm("v_pk_fma_f16 %0, %1, %2, %0 op_sel:[1,1,0] op_sel_hi:[1,0,1] neg_hi:[1,0,0]"
        : "+v"(d) : "v"(c), "v"(s));
  }
  return d;
}

template <int SR, int SI>
__device__ __forceinline__ unsigned cfma_sg(unsigned c, unsigned s, unsigned acc) {
  unsigned d;
  if constexpr (SR > 0) {
    asm("v_pk_fma_f16 %0, %1, %2, %3 op_sel_hi:[0,1,1]"
        : "=v"(d) : "v"(c), "v"(s), "v"(acc));
  } else {
    asm("v_pk_fma_f16 %0, %1, %2, %3 op_sel_hi:[0,1,1] neg_lo:[1,0,0] neg_hi:[1,0,0]"
        : "=v"(d) : "v"(c), "v"(s), "v"(acc));
  }
  if constexpr (SI > 0) {
    asm("v_pk_fma_f16 %0, %1, %2, %0 op_sel:[1,1,0] op_sel_hi:[1,0,1] neg_lo:[1,0,0]"
        : "+v"(d) : "v"(c), "v"(s));
  } else {
    asm("v_pk_fma_f16 %0, %1, %2, %0 op_sel:[1,1,0] op_sel_hi:[1,0,1] neg_hi:[1,0,0]"
        : "+v"(d) : "v"(c), "v"(s));
  }
  return d;
}

// ---------- lane-crossing (R6 config: best measured) ----------
// E=0: masks 1,2 quad_perm DPP; 8 row_ror:8 DPP; 4,16 ds_swizzle; 32 ds_permute.
// E=1: masks 1,2,8 -> ds_swizzle (e-split balances VALU/DS pipes).
// R8: the STALL source is register-starved scheduling (VGPR=40 leaves ~8
// temps; shuffles were consumed 2-4 at a time, re-exposing ~50cyc DS latency
// dozens of times per layer). Gates/ring now batch-issue ALL shuffles into
// explicit arrays before consuming (16-32 deep DS queue).
template <int MASK>
__device__ __forceinline__ int ishfl_xor(int v) {
  if constexpr (MASK == 1) {
    return __builtin_amdgcn_update_dpp(v, v, 0xB1, 0xF, 0xF, true);
  } else if constexpr (MASK == 2) {
    return __builtin_amdgcn_update_dpp(v, v, 0x4E, 0xF, 0xF, true);
  } else if constexpr (MASK == 4) {
    return __builtin_amdgcn_ds_swizzle(v, 0x101F);
  } else if constexpr (MASK == 8) {
    return __builtin_amdgcn_update_dpp(v, v, 0x128, 0xF, 0xF, true);
  } else if constexpr (MASK == 16) {
    return __builtin_amdgcn_ds_swizzle(v, 0x401F);
  } else {
    return __shfl_xor(v, MASK, 64);
  }
}

template <int MASK, int E>
__device__ __forceinline__ int ishfl_xor_e(int v) {
  if constexpr (E == 1) {
    if constexpr (MASK == 1) {
      return __builtin_amdgcn_ds_swizzle(v, 0x041F);
    } else if constexpr (MASK == 2) {
      return __builtin_amdgcn_ds_swizzle(v, 0x081F);
    } else if constexpr (MASK == 8) {
      return __builtin_amdgcn_ds_swizzle(v, 0x201F);
    } else {
      return ishfl_xor<MASK>(v);
    }
  } else {
    return ishfl_xor<MASK>(v);
  }
}

template <int MASK>
__device__ __forceinline__ float fshfl_xor(float v) {
  return __int_as_float(ishfl_xor<MASK>(__float_as_int(v)));
}

__device__ __forceinline__ unsigned readlane_u(unsigned v, int l) {
  return (unsigned)__builtin_amdgcn_readlane((int)v, l);
}

__device__ __forceinline__ float wave_sum_h(float v) {
  v += fshfl_xor<1>(v);
  v += fshfl_xor<2>(v);
  v += fshfl_xor<4>(v);
  v += fshfl_xor<8>(v);
  v += fshfl_xor<16>(v);
  v += fshfl_xor<32>(v);
  return v;
}

// Round-to-nearest f16 pack (cvt_pkrtz is RTZ -> R6's 1.5% norm contraction).
__device__ __forceinline__ unsigned pack_h2_rtn(float re, float im) {
  return (unsigned)__half_as_ushort(__float2half(re)) |
         ((unsigned)__half_as_ushort(__float2half(im)) << 16);
}

// Cross gate on lane bit LB, both elements, full 16 regs — TWO-PHASE:
// phase 1 issues all 32 shuffles into p[][] (DS queue fills), phase 2 does
// the 64 pk updates (drains with amortized latency).
// DEF=true (LB=5 only): preceding ring's q9 xor32 on ODD regs was deferred;
// for odd r the gate's own xor32 cancels it -> operand roles swap
// (new = A*p + B*s). Bit-exact (verified R7). After the gate, layout is true.
template <int LB, bool DEF = false>
__device__ __forceinline__ void cross_gate2(unsigned (&sv)[2][16],
                                            const unsigned (&u00)[2],
                                            const unsigned (&u01)[2], int lane) {
  const bool bit = (lane & (1 << LB)) != 0;
  unsigned A[2], B[2];
#pragma unroll
  for (int e = 0; e < 2; ++e) {
    A[e] = bit ? (u00[e] ^ 0x80000000u) : u00[e];
    B[e] = bit ? (u01[e] ^ 0x00008000u) : u01[e];
  }
  unsigned p[2][16];
#pragma unroll
  for (int r = 0; r < 16; ++r) {
    p[0][r] = (unsigned)ishfl_xor_e<(1 << LB), 0>((int)sv[0][r]);
    p[1][r] = (unsigned)ishfl_xor_e<(1 << LB), 1>((int)sv[1][r]);
  }
#pragma unroll
  for (int r = 0; r < 16; ++r) {
    if (DEF && (r & 1)) {
      sv[0][r] = cfma_sg<1, 1>(B[0], sv[0][r], cmul_sg<1, 1>(A[0], p[0][r]));
      sv[1][r] = cfma_sg<1, 1>(B[1], sv[1][r], cmul_sg<1, 1>(A[1], p[1][r]));
    } else {
      sv[0][r] = cfma_sg<1, 1>(B[0], p[0][r], cmul_sg<1, 1>(A[0], sv[0][r]));
      sv[1][r] = cfma_sg<1, 1>(B[1], p[1][r], cmul_sg<1, 1>(A[1], sv[1][r]));
    }
  }
}

// Layer-0 cross gate: regs 1..15 are exactly zero, only r=0 carries amplitude.
template <int LB>
__device__ __forceinline__ void cross_gate2_r0(unsigned (&sv)[2][16],
                                               const unsigned (&u00)[2],
                                               const unsigned (&u01)[2], int lane) {
  const bool bit = (lane & (1 << LB)) != 0;
  unsigned p0 = (unsigned)ishfl_xor_e<(1 << LB), 0>((int)sv[0][0]);
  unsigned p1 = (unsigned)ishfl_xor_e<(1 << LB), 1>((int)sv[1][0]);
  {
    const unsigned A = bit ? (u00[0] ^ 0x80000000u) : u00[0];
    const unsigned B = bit ? (u01[0] ^ 0x00008000u) : u01[0];
    sv[0][0] = cfma_sg<1, 1>(B, p0, cmul_sg<1, 1>(A, sv[0][0]));
  }
  {
    const unsigned A = bit ? (u00[1] ^ 0x80000000u) : u00[1];
    const unsigned B = bit ? (u01[1] ^ 0x00008000u) : u01[1];
    sv[1][0] = cfma_sg<1, 1>(B, p1, cmul_sg<1, 1>(A, sv[1][0]));
  }
}

// Register-local gate on reg bit RB, full (both pair halves nonzero).
template <int RB>
__device__ __forceinline__ void local_gate2(unsigned (&sv)[2][16],
                                            const unsigned (&u00)[2],
                                            const unsigned (&u01)[2]) {
#pragma unroll
  for (int rlo = 0; rlo < 16; ++rlo) {
    if (rlo & (1 << RB)) continue;
    const int rhi = rlo | (1 << RB);
#pragma unroll
    for (int e = 0; e < 2; ++e) {
      unsigned lo = sv[e][rlo], hi = sv[e][rhi];
      sv[e][rlo] = cfma_sg<1, 1>(u01[e], hi, cmul_sg<1, 1>(u00[e], lo));
      sv[e][rhi] = cfma_sg<1, -1>(u00[e], hi, cmul_sg<-1, 1>(u01[e], lo));
    }
  }
}

// Layer-0 local gate: live regs before gate RB are {r : r & ((2<<RB)-1) == 0};
// hi half of every pair is exactly zero -> pure cmul fill (2 pk each).
template <int RB>
__device__ __forceinline__ void local_gate2_fill(unsigned (&sv)[2][16],
                                                 const unsigned (&u00)[2],
                                                 const unsigned (&u01)[2]) {
#pragma unroll
  for (int rlo = 0; rlo < 16; ++rlo) {
    if (rlo & ((2 << RB) - 1)) continue;  // only live, pair-base regs
    const int rhi = rlo | (1 << RB);
#pragma unroll
    for (int e = 0; e < 2; ++e) {
      unsigned lo = sv[e][rlo];
      sv[e][rhi] = cmul_sg<-1, 1>(u01[e], lo);
      sv[e][rlo] = cmul_sg<1, 1>(u00[e], lo);
    }
  }
}

// CNOT ring, q -> q+1 mod 10 (composed), both elements. BATCHED:
// all 32 ds_bpermute issued into t[][] first; then q5 (cond swap on lane
// bit0) is COMPOSED with the q6..8 register gather into one cndmask pass:
//   new[j] = c5 ? t[m(j)^8] : t[m(j)]
// (32 cndmask replace 64 cndmask + 40 swap movs of the old 2-pass form).
// apply_q9=false: q9's xor32 on odd regs stays PENDING (consumed by next
// layer's wire0 gate via cross_gate2<5,true>).
__device__ __forceinline__ void ring_step(unsigned (&sv)[2][16], int lane,
                                          int permSrc, bool apply_q9) {
  unsigned t[2][16];
#pragma unroll
  for (int r = 0; r < 16; ++r) {
    t[0][r] = (unsigned)__shfl((int)sv[0][r], permSrc);
    t[1][r] = (unsigned)__shfl((int)sv[1][r], permSrc);
  }
  const bool c5 = (lane & 1) != 0;
  // m(j): composed q6..8 register gather (new[j] = mid[m(j)], mid = q5(old))
  constexpr int m[16] = {0, 1, 3, 2, 6, 7, 5, 4, 12, 13, 15, 14, 10, 11, 9, 8};
#pragma unroll
  for (int j = 0; j < 16; ++j) {
#pragma unroll
    for (int e = 0; e < 2; ++e)
      sv[e][j] = c5 ? t[e][m[j] ^ 8] : t[e][m[j]];
  }
  // q9: control wire9 = reg bit0, target wire0 = lane bit5 -> odd r: xor32
  if (apply_q9) {
#pragma unroll
    for (int r = 1; r < 16; r += 2) {
      sv[0][r] = (unsigned)ishfl_xor<32>((int)sv[0][r]);
      sv[1][r] = (unsigned)ishfl_xor<32>((int)sv[1][r]);
    }
  }
}

// One wave simulates 2 batch elements (register-interleaved). State index
// i = lane*16 + r. Wire q at bit (9-q): wires 0..5 -> lane bits 5..0,
// wires 6..9 -> reg bits 3..0.
// Layer 0: sparsity-specialized (|0...0> start) — bit-identical.
// R11: TLP, not ILP — NE=2. R12/R13/R15: dur tracks VALU count but is ~60%
// stall; pipe re-routing never helped. R16 (this round): stall = register-
// starved shuffle scheduling at VGPR=40 (8 spare regs -> DS latency exposed
// serially). Two-phase gates + batched ring force 16-32-deep shuffle queues.
// launch_bounds(256,4): 128-VGPR budget for the wide live ranges (R10: a
// 64-cap spills; watch FETCH_SIZE ~1.5MB as the no-spill guard).
__global__ __launch_bounds__(256, 4) void qsim_kernel(
    const float* __restrict__ x, const float* __restrict__ w,
    float* __restrict__ out, int batch) {
  const int lane = threadIdx.x & 63;
  const int wv = blockIdx.x * 4 + (threadIdx.x >> 6);
  const int permSrc = lane ^ (lane >> 1);  // composed CNOT(q,q+1), q=0..4

  // weight-only gate factors: lane j<40 owns gate j = l*10+q
  float Pr = 0.f, Pi = 0.f, Qr = 0.f, Qi = 0.f;
  if (lane < NA) {
    float w0 = w[2 * lane], w1 = w[2 * lane + 1];
    float r0 = w0 * (0.5f * INV_2PI_F), r1 = w1 * (0.5f * INV_2PI_F);
    float sphi = __builtin_amdgcn_sinf(r0), cphi = __builtin_amdgcn_cosf(r0);
    float sw = __builtin_amdgcn_sinf(r1), cw = __builtin_amdgcn_cosf(r1);
    Pr = cw * cphi; Pi = -cw * sphi;  // P = cos(w1/2) e^{-i w0/2}
    Qr = sw * cphi; Qi = sw * sphi;   // Q = sin(w1/2) e^{+i w0/2}
  }

  // ---- prologue for both elements: SU(2) coefs packed f16 (RTN) ----
  unsigned U00[2] = {0u, 0u}, U01[2] = {0u, 0u};
#pragma unroll
  for (int e = 0; e < 2; ++e) {
    const int wid = wv * 2 + e;
    const int widc = wid < batch ? wid : batch - 1;
    if (lane < NA) {
      float xv = x[widc * NA + lane];
      // a = (pi/2)*atan(x) radians -> atan(x)/4 revolutions
      float rev = 0.25f * atanf(xv);
      float sa = __builtin_amdgcn_sinf(rev);
      float ca = __builtin_amdgcn_cosf(rev);
      float u00r = ca * Pr - sa * Qr;
      float u00i = ca * Pi - sa * Qi;
      float u01r = -(sa * Pr + ca * Qr);
      float u01i = -(sa * Pi + ca * Qi);
      U00[e] = pack_h2_rtn(u00r, u00i);
      U01[e] = pack_h2_rtn(u01r, u01i);
    }
  }

  unsigned sv[2][16];
#pragma unroll
  for (int r = 0; r < 16; ++r) { sv[0][r] = 0u; sv[1][r] = 0u; }
  if (lane == 0) { sv[0][0] = 0x3C00u; sv[1][0] = 0x3C00u; }  // |0...0>

#define GET_U(j)                                                     \
  const unsigned u00[2] = {readlane_u(U00[0], (j)), readlane_u(U00[1], (j))}; \
  const unsigned u01[2] = {readlane_u(U01[0], (j)), readlane_u(U01[1], (j))}

  // ---------- layer 0: sparsity-specialized ----------
  { GET_U(0); cross_gate2_r0<5>(sv, u00, u01, lane); }  // wire0
  { GET_U(1); cross_gate2_r0<4>(sv, u00, u01, lane); }  // wire1
  { GET_U(2); cross_gate2_r0<3>(sv, u00, u01, lane); }  // wire2
  { GET_U(3); cross_gate2_r0<2>(sv, u00, u01, lane); }  // wire3
  { GET_U(4); cross_gate2_r0<1>(sv, u00, u01, lane); }  // wire4
  { GET_U(5); cross_gate2_r0<0>(sv, u00, u01, lane); }  // wire5
  { GET_U(6); local_gate2_fill<3>(sv, u00, u01); }      // wire6: 1 -> 2 live
  { GET_U(7); local_gate2_fill<2>(sv, u00, u01); }      // wire7: 2 -> 4
  { GET_U(8); local_gate2_fill<1>(sv, u00, u01); }      // wire8: 4 -> 8
  { GET_U(9); local_gate2_fill<0>(sv, u00, u01); }      // wire9: 8 -> 16
  ring_step(sv, lane, permSrc, /*apply_q9=*/false);     // q9 -> layer1 wire0

  // ---------- layers 1..3: dense ----------
#pragma unroll 1
  for (int l = 1; l < NL; ++l) {
    const int j0 = l * NQ;
    // wire0 consumes the deferred q9 xor32 (odd regs) from the previous ring
    { GET_U(j0 + 0); cross_gate2<5, true>(sv, u00, u01, lane); }
    { GET_U(j0 + 1); cross_gate2<4>(sv, u00, u01, lane); }  // wire1: lane bit4
    { GET_U(j0 + 2); cross_gate2<3>(sv, u00, u01, lane); }  // wire2: lane bit3
    { GET_U(j0 + 3); cross_gate2<2>(sv, u00, u01, lane); }  // wire3: lane bit2
    { GET_U(j0 + 4); cross_gate2<1>(sv, u00, u01, lane); }  // wire4: lane bit1
    { GET_U(j0 + 5); cross_gate2<0>(sv, u00, u01, lane); }  // wire5: lane bit0
    { GET_U(j0 + 6); local_gate2<3>(sv, u00, u01); }        // wire6: reg bit3
    { GET_U(j0 + 7); local_gate2<2>(sv, u00, u01); }        // wire7: reg bit2
    { GET_U(j0 + 8); local_gate2<1>(sv, u00, u01); }        // wire8: reg bit1
    { GET_U(j0 + 9); local_gate2<0>(sv, u00, u01); }        // wire9: reg bit0
    // rings after layers 1,2: defer q9; final ring: apply (epilogue needs
    // true layout)
    ring_step(sv, lane, permSrc, /*apply_q9=*/(l == NL - 1));
  }
#undef GET_U

  // ---------- epilogue (f32, v_dot2_f32_f16 accumulation), per element ----------
#pragma unroll
  for (int e = 0; e < 2; ++e) {
    const int wid = wv * 2 + e;
    float tot = 0.f, t0 = 0.f, t1 = 0.f, t2 = 0.f, t3 = 0.f;
#pragma unroll
    for (int r = 0; r < 16; ++r) {
      h2 a = __builtin_bit_cast(h2, sv[e][r]);
      tot = __builtin_amdgcn_fdot2(a, a, tot, false);
      if (r & 1) t0 = __builtin_amdgcn_fdot2(a, a, t0, false);
      if (r & 2) t1 = __builtin_amdgcn_fdot2(a, a, t1, false);
      if (r & 4) t2 = __builtin_amdgcn_fdot2(a, a, t2, false);
      if (r & 8) t3 = __builtin_amdgcn_fdot2(a, a, t3, false);
    }
    const float S3 = wave_sum_h(t3);
    const float S2 = wave_sum_h(t2);
    const float S1 = wave_sum_h(t1);
    const float S0 = wave_sum_h(t0);
    // renormalize: true Z = (P0-P1)/(P0+P1) cancels f16 norm drift
    const float N = wave_sum_h(tot);
    const float invN = 1.0f / N;
    // Walsh-Hadamard across lanes: lane L holds sum_i (-1)^popcnt(L&i) tot_i.
    float v = tot, h;
    h = fshfl_xor<1>(v);  v = (lane & 1)  ? h - v : v + h;
    h = fshfl_xor<2>(v);  v = (lane & 2)  ? h - v : v + h;
    h = fshfl_xor<4>(v);  v = (lane & 4)  ? h - v : v + h;
    h = fshfl_xor<8>(v);  v = (lane & 8)  ? h - v : v + h;
    h = fshfl_xor<16>(v); v = (lane & 16) ? h - v : v + h;
    h = fshfl_xor<32>(v); v = (lane & 32) ? h - v : v + h;

    if (wid < batch) {
      float* o = out + wid * NQ;
      if (lane == 32) o[0] = v * invN;  // wire0 sign = lane bit5
      if (lane == 16) o[1] = v * invN;
      if (lane == 8)  o[2] = v * invN;
      if (lane == 4)  o[3] = v * invN;
      if (lane == 2)  o[4] = v * invN;
      if (lane == 1)  o[5] = v * invN;  // wire5 sign = lane bit0
      if (lane == 0) {
        o[6] = (v - 2.f * S3) * invN;  // wire6 = reg bit3; v(lane0) = sum(tot)
        o[7] = (v - 2.f * S2) * invN;
        o[8] = (v - 2.f * S1) * invN;
        o[9] = (v - 2.f * S0) * invN;
      }
    }
  }
}

extern "C" void kernel_launch(void* const* d_in, const int* in_sizes, int n_in,
                              void* d_out, int out_size, void* d_ws, size_t ws_size,
                              hipStream_t stream) {
  const float* x = (const float*)d_in[0];
  const float* w = (const float*)d_in[1];
  float* out = (float*)d_out;
  const int batch = in_sizes[0] / NA;
  const int waves = (batch + 1) / 2;   // 2 elements per wave
  const int blocks = (waves + 3) / 4;  // 4 independent waves per 256-thread block
  qsim_kernel<<<blocks, 256, 0, stream>>>(x, w, out, batch);
}